// Round 4
// baseline (410.415 us; speedup 1.0000x reference)
//
#include <hip/hip_runtime.h>

typedef unsigned short u16;
typedef unsigned int u32;
typedef __attribute__((ext_vector_type(8))) short bf16x8;
typedef __attribute__((ext_vector_type(8))) u16 u16x8;
typedef __attribute__((ext_vector_type(4))) float f32x4;

__device__ __forceinline__ u16 f2bf(float f) {
  u32 u = __builtin_bit_cast(u32, f);
  u32 r = (u + 0x7fffu + ((u >> 16) & 1u)) >> 16;
  return (u16)r;
}
__device__ __forceinline__ float bf2f(u16 h) {
  u32 u = ((u32)h) << 16;
  return __builtin_bit_cast(float, u);
}

__device__ __forceinline__ void gload16(const u16* g, u16* l) {
  __builtin_amdgcn_global_load_lds(
      (const __attribute__((address_space(1))) void*)g,
      (__attribute__((address_space(3))) void*)l, 16, 0, 0);
}

// issue one 128x64 half-tile (2 x global_load_lds of 64 rows each)
__device__ __forceinline__ void stage_half(const u16* gsrc, u16* ldst,
                                           long ld64) {
  gload16(gsrc, ldst);
  gload16(gsrc + ld64, ldst + 4096);
}

__device__ __forceinline__ void dsa(bf16x8 (&af)[2][2], const u16* base,
                                    u32 off0, u32 off1) {
  af[0][0] = *(const bf16x8*)(base + off0);
  af[0][1] = *(const bf16x8*)(base + off1);
  af[1][0] = *(const bf16x8*)(base + 1024 + off0);
  af[1][1] = *(const bf16x8*)(base + 1024 + off1);
}

__device__ __forceinline__ void dsb(bf16x8 (&bfr)[4][2], const u16* base,
                                    u32 off0, u32 off1) {
#pragma unroll
  for (int fc = 0; fc < 4; ++fc) {
    bfr[fc][0] = *(const bf16x8*)(base + fc * 1024 + off0);
    bfr[fc][1] = *(const bf16x8*)(base + fc * 1024 + off1);
  }
}

template <int Q>
__device__ __forceinline__ void mfma_quad(f32x4 (&acc)[8][4],
                                          const bf16x8 (&af)[2][2],
                                          const bf16x8 (&bfr)[4][2]) {
#pragma unroll
  for (int fc = 0; fc < 4; ++fc) {
    acc[2 * Q][fc] = __builtin_amdgcn_mfma_f32_16x16x32_bf16(
        af[0][0], bfr[fc][0], acc[2 * Q][fc], 0, 0, 0);
    acc[2 * Q + 1][fc] = __builtin_amdgcn_mfma_f32_16x16x32_bf16(
        af[1][0], bfr[fc][0], acc[2 * Q + 1][fc], 0, 0, 0);
    acc[2 * Q][fc] = __builtin_amdgcn_mfma_f32_16x16x32_bf16(
        af[0][1], bfr[fc][1], acc[2 * Q][fc], 0, 0, 0);
    acc[2 * Q + 1][fc] = __builtin_amdgcn_mfma_f32_16x16x32_bf16(
        af[1][1], bfr[fc][1], acc[2 * Q + 1][fc], 0, 0, 0);
  }
}

// asm s_barrier with memory clobber: a COMPILER memory fence (ds_read and
// global_load_lds cannot cross), while register-only MFMA/VALU stay free to
// schedule.  This is the minimal fence that fixes the round-2 DMA-hoist race
// without m141-style full order-pinning.
#define BAR asm volatile("s_barrier" ::: "memory")

// barrier -> wait own ds_reads -> pin (rule #18: MFMA would hoist past lgkm)
#define PH_HEAD                                         \
  do {                                                  \
    BAR;                                                \
    asm volatile("s_waitcnt lgkmcnt(0)" ::: "memory");  \
    __builtin_amdgcn_sched_barrier(0);                  \
  } while (0)

#define PH_TAIL(Q)                                      \
  do {                                                  \
    __builtin_amdgcn_s_setprio(1);                      \
    mfma_quad<Q>(acc, af, bfr);                         \
    __builtin_amdgcn_s_setprio(0);                      \
    BAR;                                                \
  } while (0)

#define STG_A(tile, half)                                                 \
  if ((tile) < NT)                                                        \
  stage_half(gA + (long)(half) * 128 * lda + (long)(tile) * 64,           \
             As + (((tile)&1) * 2 + (half)) * 8192 + wofs, lda64)

#define STG_B(tile, half)                                                 \
  if ((tile) < NT)                                                        \
  stage_half(gB + (long)(half) * 128 * ldb + (long)(tile) * 64,           \
             Bs + (((tile)&1) * 2 + (half)) * 8192 + wofs, ldb64)

// ---------------------------------------------------------------------------
// 256x256-tile bf16 GEMM, BK=64, 8 waves (2M x 4N), 8-phase schedule with
// counted vmcnt, st-swizzled LDS (slot ^= row&7 on both stage-source and
// ds_read).  C = A (MxK, lda) * Bt^T (Bt: NxK, ldb) [+ bias].
// Staging (prefetch-depth-tuned; all placements runtime-safe under program
// order, compile order enforced by asm-memory barriers):
//   ph1: A(t+1,h0)+A(t+1,h1)   ph2: B(t+2,h0)   ph3: B(t+2,h1)
//   ph4: vmcnt(4) -> tile t+1 landed (newest 4 = B(t+2) pair)
//   ph5: A(t+2,h0)+A(t+2,h1)   ph6: B(t+3,h0)   ph7: B(t+3,h1)
//   ph8: vmcnt(4) -> tile t+2 landed (newest 4 = B(t+3) pair)
// Slack: A waited 3 phases after issue, B 5-6 phases.  Last iteration:
// B-staging predicated off -> ph4 must drain with vmcnt(0) (else the newest-4
// window would leave A(NT-1) in flight).
// EPI: 0 = f32 out, 1 = bf16 out, 2 = bf16 QK-part (cols<1536, ldc) +
// V-part written transposed into VTout[b][d][s] (b = row>>12).
// ---------------------------------------------------------------------------
template <int EPI, bool BIAS>
__global__ __launch_bounds__(512, 2) void gemm256(
    const u16* __restrict__ A, long lda, long sA, const u16* __restrict__ Bt,
    long ldb, long sB, void* __restrict__ Cout, long ldc, long sC,
    const float* __restrict__ bias, int NT, u16* __restrict__ VTout) {
  __shared__ u16 As[32768];  // [buf2][half2][128][64]
  __shared__ u16 Bs[32768];

  const int z = blockIdx.z;
  A += (long)z * sA;
  Bt += (long)z * sB;

  const int tid = threadIdx.x;
  const int w = tid >> 6, lane = tid & 63;
  const int wm = w >> 2, wn = w & 3;
  const int g = lane >> 4, l15 = lane & 15, l7 = lane & 7;
  const int m0 = blockIdx.x * 256;
  const int n0 = blockIdx.y * 256;

  // ds_read swizzled lane offsets (elements): slot = (ks*4+g) ^ (row&7)
  const u32 off0 = (u32)(((0 + g) ^ l7) * 8);
  const u32 off1 = (u32)(((4 + g) ^ l7) * 8);
  const u16* pA = As + wm * 8192 + l15 * 64;
  const u16* pB = Bs + (wn >> 1) * 8192 + ((wn & 1) * 64 + l15) * 64;

  // staging: thread t covers LDS bytes t*16 of an 8KB chunk; source column
  // pre-swizzled so LDS content obeys slot ^= row&7.
  const int trow = tid >> 3;
  const int perm = (tid & 7) ^ ((tid >> 3) & 7);
  const u16* gA = A + (long)(m0 + trow) * lda + perm * 8;
  const u16* gB = Bt + (long)(n0 + trow) * ldb + perm * 8;
  const long lda64 = lda * 64, ldb64 = ldb * 64;
  const u32 wofs = w * 512;  // elements; + lane*16B implicit in DMA

  f32x4 acc[8][4];
#pragma unroll
  for (int i = 0; i < 8; ++i)
#pragma unroll
    for (int j = 0; j < 4; ++j) acc[i][j] = (f32x4){0.f, 0.f, 0.f, 0.f};

  // prologue: tile0 (A+B) -> buf0, tile1 B -> buf1; wait leaves B(1) in flight
  stage_half(gA, As + 0 * 8192 + wofs, lda64);
  stage_half(gA + 128 * lda, As + 1 * 8192 + wofs, lda64);
  stage_half(gB, Bs + 0 * 8192 + wofs, ldb64);
  stage_half(gB + 128 * ldb, Bs + 1 * 8192 + wofs, ldb64);
  stage_half(gB + 64, Bs + 2 * 8192 + wofs, ldb64);
  stage_half(gB + 128 * ldb + 64, Bs + 3 * 8192 + wofs, ldb64);
  asm volatile("s_waitcnt vmcnt(4)" ::: "memory");
  BAR;

  bf16x8 af[2][2], bfr[4][2];
  const int niter = NT >> 1;
  for (int it = 0; it < niter; ++it) {
    const int t0 = it * 2;
    // ---- tile t0 (buf0) ----
    dsb(bfr, pB, off0, off1);  // ph1
    dsa(af, pA, off0, off1);
    STG_A(t0 + 1, 0);
    STG_A(t0 + 1, 1);
    PH_HEAD;
    PH_TAIL(0);
    dsa(af, pA + 2048, off0, off1);  // ph2
    STG_B(t0 + 2, 0);
    PH_HEAD;
    PH_TAIL(1);
    dsa(af, pA + 4096, off0, off1);  // ph3
    STG_B(t0 + 2, 1);
    PH_HEAD;
    PH_TAIL(2);
    dsa(af, pA + 6144, off0, off1);  // ph4
    if (it + 1 == niter) {
      asm volatile("s_waitcnt vmcnt(0)" ::: "memory");
    } else {
      asm volatile("s_waitcnt vmcnt(4)" ::: "memory");
    }
    PH_HEAD;
    PH_TAIL(3);
    // ---- tile t0+1 (buf1) ----
    dsb(bfr, pB + 16384, off0, off1);  // ph5
    dsa(af, pA + 16384, off0, off1);
    STG_A(t0 + 2, 0);
    STG_A(t0 + 2, 1);
    PH_HEAD;
    PH_TAIL(0);
    dsa(af, pA + 16384 + 2048, off0, off1);  // ph6
    STG_B(t0 + 3, 0);
    PH_HEAD;
    PH_TAIL(1);
    dsa(af, pA + 16384 + 4096, off0, off1);  // ph7
    STG_B(t0 + 3, 1);
    PH_HEAD;
    PH_TAIL(2);
    dsa(af, pA + 16384 + 6144, off0, off1);  // ph8
    asm volatile("s_waitcnt vmcnt(4)" ::: "memory");
    PH_HEAD;
    PH_TAIL(3);
  }

  // epilogue: C/D layout col = lane&15, row = (lane>>4)*4 + reg
  const int erow0 = m0 + wm * 128 + (lane >> 4) * 4;
  const int ecol0 = n0 + wn * 64 + l15;
#pragma unroll
  for (int fr = 0; fr < 8; ++fr) {
#pragma unroll
    for (int fc = 0; fc < 4; ++fc) {
      const int col = ecol0 + fc * 16;
      const float badd = BIAS ? bias[col] : 0.f;
#pragma unroll
      for (int r = 0; r < 4; ++r) {
        const long row = erow0 + fr * 16 + r;
        const float v = acc[fr][fc][r] + badd;
        if (EPI == 0) {
          ((float*)Cout)[(long)z * sC + row * ldc + col] = v;
        } else if (EPI == 1) {
          ((u16*)Cout)[(long)z * sC + row * ldc + col] = f2bf(v);
        } else {
          if (n0 < 1536) {
            ((u16*)Cout)[row * ldc + col] = f2bf(v);
          } else {
            const long b = row >> 12, s = row & 4095;
            VTout[(b * 768 + (col - 1536)) * 4096 + s] = f2bf(v);
          }
        }
      }
    }
  }
}

// ---------------------------------------------------------------------------
__global__ __launch_bounds__(256) void f32_to_bf16_kernel(
    const float* __restrict__ in, u16* __restrict__ out, long n) {
  long i0 = (long)blockIdx.x * 256 + threadIdx.x;
  long stride = (long)gridDim.x * 256;
  long n4 = n >> 2;
  for (long i = i0; i < n4; i += stride) {
    float4 f = ((const float4*)in)[i];
    ushort4 o = make_ushort4(f2bf(f.x), f2bf(f.y), f2bf(f.z), f2bf(f.w));
    ((ushort4*)out)[i] = o;
  }
}

// Wcat_t[2304][768] = concat(Wq^T * qs, Wk^T, Wv^T) as bf16
__global__ __launch_bounds__(256) void wcat_kernel(
    const float* __restrict__ Wq, const float* __restrict__ Wk,
    const float* __restrict__ Wv, u16* __restrict__ Wt, float qs) {
  __shared__ float t[64][65];
  const int kt = blockIdx.x;  // 0..11
  const int nt = blockIdx.y;  // 0..35
  const int sel = nt / 12;
  const float* W = sel == 0 ? Wq : (sel == 1 ? Wk : Wv);
  const float scale = sel == 0 ? qs : 1.f;
  const int n0 = (nt % 12) * 64, k0 = kt * 64;
#pragma unroll
  for (int i = 0; i < 16; ++i) {
    int idx = i * 256 + threadIdx.x;
    int r = idx >> 6, c = idx & 63;
    t[r][c] = W[(long)(k0 + r) * 768 + (n0 + c)];
  }
  __syncthreads();
#pragma unroll
  for (int i = 0; i < 16; ++i) {
    int idx = i * 256 + threadIdx.x;
    int ro = idx >> 6, co = idx & 63;
    Wt[(long)(nt * 64 + ro) * 768 + (k0 + co)] = f2bf(t[co][ro] * scale);
  }
}

__global__ __launch_bounds__(256) void bcat_kernel(
    const float* __restrict__ bq, const float* __restrict__ bk,
    const float* __restrict__ bv, float* __restrict__ bc, float qs) {
  int i = blockIdx.x * 256 + threadIdx.x;
  if (i < 2304)
    bc[i] = i < 768 ? bq[i] * qs : (i < 1536 ? bk[i - 768] : bv[i - 1536]);
}

// in-place row softmax over 4096 bf16 per row; one block (256 thr) per row.
__global__ __launch_bounds__(256) void softmax_rows_kernel(u16* __restrict__ Sd) {
  const long row = blockIdx.x;
  u16* p = Sd + row * 4096;
  const int tid = threadIdx.x;
  u16x8 a0 = *(const u16x8*)(p + tid * 8);
  u16x8 a1 = *(const u16x8*)(p + 2048 + tid * 8);
  float v[16];
#pragma unroll
  for (int j = 0; j < 8; ++j) {
    v[j] = bf2f(a0[j]);
    v[8 + j] = bf2f(a1[j]);
  }
  float mx = v[0];
#pragma unroll
  for (int j = 1; j < 16; ++j) mx = fmaxf(mx, v[j]);
#pragma unroll
  for (int o = 32; o > 0; o >>= 1) mx = fmaxf(mx, __shfl_xor(mx, o, 64));
  __shared__ float red[8];
  if ((tid & 63) == 0) red[tid >> 6] = mx;
  __syncthreads();
  mx = fmaxf(fmaxf(red[0], red[1]), fmaxf(red[2], red[3]));
  float e[16], s = 0.f;
  const float L2E = 1.4426950408889634f;
#pragma unroll
  for (int j = 0; j < 16; ++j) {
    e[j] = exp2f((v[j] - mx) * L2E);
    s += e[j];
  }
#pragma unroll
  for (int o = 32; o > 0; o >>= 1) s += __shfl_xor(s, o, 64);
  if ((tid & 63) == 0) red[4 + (tid >> 6)] = s;
  __syncthreads();
  s = (red[4] + red[5]) + (red[6] + red[7]);
  const float inv = 1.f / s;
  u16x8 o0, o1;
#pragma unroll
  for (int j = 0; j < 8; ++j) {
    o0[j] = f2bf(e[j] * inv);
    o1[j] = f2bf(e[8 + j] * inv);
  }
  *(u16x8*)(p + tid * 8) = o0;
  *(u16x8*)(p + 2048 + tid * 8) = o1;
}

// ---------------------------------------------------------------------------
extern "C" void kernel_launch(void* const* d_in, const int* in_sizes, int n_in,
                              void* d_out, int out_size, void* d_ws,
                              size_t ws_size, hipStream_t stream) {
  const float* x = (const float*)d_in[0];
  const float* Wq = (const float*)d_in[1];
  const float* bq = (const float*)d_in[2];
  const float* Wk = (const float*)d_in[3];
  const float* bk = (const float*)d_in[4];
  const float* Wv = (const float*)d_in[5];
  const float* bv = (const float*)d_in[6];
  float* out = (float*)d_out;

  const float qs = 0.036084391824351615f;  // 1/sqrt(768)

  // workspace carve
  char* p = (char*)d_ws;
  u16* Wcat = (u16*)p;  p += (size_t)2304 * 768 * 2;   // 3.54 MB
  float* bc = (float*)p; p += (size_t)2304 * 4;         // 9.2 KB
  u16* xbf = (u16*)p;   p += (size_t)16384 * 768 * 2;  // 25.2 MB
  u16* QK = (u16*)p;    p += (size_t)16384 * 1536 * 2; // 50.3 MB
  u16* VT = (u16*)p;    p += (size_t)4 * 768 * 4096 * 2; // 25.2 MB
  u16* Sbuf = (u16*)p;
  const size_t base = (size_t)(p - (char*)d_ws);
  const size_t sOne = (size_t)4096 * 4096 * 2;  // 33.6 MB
  int grp = 1;
  if (ws_size >= base + 4 * sOne) grp = 4;
  else if (ws_size >= base + 2 * sOne) grp = 2;

  f32_to_bf16_kernel<<<2048, 256, 0, stream>>>(x, xbf, (long)16384 * 768);
  wcat_kernel<<<dim3(12, 36), 256, 0, stream>>>(Wq, Wk, Wv, Wcat, qs);
  bcat_kernel<<<9, 256, 0, stream>>>(bq, bk, bv, bc, qs);

  // fused QKV projection: A=xbf (16384x768), Bt=Wcat (2304x768)
  // cols 0-1535 -> QK (ldc 1536), cols 1536+ -> VT[b][d][s]
  gemm256<2, true><<<dim3(64, 9, 1), 512, 0, stream>>>(
      xbf, 768, 0, Wcat, 768, 0, QK, 1536, 0, bc, 12, VT);

  for (int b0 = 0; b0 < 4; b0 += grp) {
    // scores: A=Q (cols 0-767 of QK), Bt=K (cols 768-1535), per batch
    gemm256<1, false><<<dim3(16, 16, grp), 512, 0, stream>>>(
        QK + (long)b0 * 4096 * 1536, 1536, (long)4096 * 1536,
        QK + 768 + (long)b0 * 4096 * 1536, 1536, (long)4096 * 1536, Sbuf, 4096,
        (long)4096 * 4096, nullptr, 12, nullptr);
    softmax_rows_kernel<<<grp * 4096, 256, 0, stream>>>(Sbuf);
    // out = P * V: A=Sbuf, Bt=VT (768x4096 per batch)
    gemm256<0, false><<<dim3(16, 3, grp), 512, 0, stream>>>(
        Sbuf, 4096, (long)4096 * 4096, VT + (long)b0 * 768 * 4096, 4096,
        (long)768 * 4096, out + (long)b0 * 4096 * 768, 768, (long)4096 * 768,
        nullptr, 64, nullptr);
  }
}

// Round 5
// 379.275 us; speedup vs baseline: 1.0821x; 1.0821x over previous
//
#include <hip/hip_runtime.h>

typedef unsigned short u16;
typedef unsigned int u32;
typedef __attribute__((ext_vector_type(8))) short bf16x8;
typedef __attribute__((ext_vector_type(8))) u16 u16x8;
typedef __attribute__((ext_vector_type(4))) float f32x4;

__device__ __forceinline__ u16 f2bf(float f) {
  u32 u = __builtin_bit_cast(u32, f);
  u32 r = (u + 0x7fffu + ((u >> 16) & 1u)) >> 16;
  return (u16)r;
}
__device__ __forceinline__ float bf2f(u16 h) {
  u32 u = ((u32)h) << 16;
  return __builtin_bit_cast(float, u);
}

__device__ __forceinline__ void gload16(const u16* g, u16* l) {
  __builtin_amdgcn_global_load_lds(
      (const __attribute__((address_space(1))) void*)g,
      (__attribute__((address_space(3))) void*)l, 16, 0, 0);
}

// issue one 128x64 half-tile (2 x global_load_lds of 64 rows each)
__device__ __forceinline__ void stage_half(const u16* gsrc, u16* ldst,
                                           long ld64) {
  gload16(gsrc, ldst);
  gload16(gsrc + ld64, ldst + 4096);
}

__device__ __forceinline__ void dsa(bf16x8 (&af)[2][2], const u16* base,
                                    u32 off0, u32 off1) {
  af[0][0] = *(const bf16x8*)(base + off0);
  af[0][1] = *(const bf16x8*)(base + off1);
  af[1][0] = *(const bf16x8*)(base + 1024 + off0);
  af[1][1] = *(const bf16x8*)(base + 1024 + off1);
}

__device__ __forceinline__ void dsb(bf16x8 (&bfr)[4][2], const u16* base,
                                    u32 off0, u32 off1) {
#pragma unroll
  for (int fc = 0; fc < 4; ++fc) {
    bfr[fc][0] = *(const bf16x8*)(base + fc * 1024 + off0);
    bfr[fc][1] = *(const bf16x8*)(base + fc * 1024 + off1);
  }
}

template <int Q>
__device__ __forceinline__ void mfma_quad(f32x4 (&acc)[8][4],
                                          const bf16x8 (&af)[2][2],
                                          const bf16x8 (&bfr)[4][2]) {
#pragma unroll
  for (int fc = 0; fc < 4; ++fc) {
    acc[2 * Q][fc] = __builtin_amdgcn_mfma_f32_16x16x32_bf16(
        af[0][0], bfr[fc][0], acc[2 * Q][fc], 0, 0, 0);
    acc[2 * Q + 1][fc] = __builtin_amdgcn_mfma_f32_16x16x32_bf16(
        af[1][0], bfr[fc][0], acc[2 * Q + 1][fc], 0, 0, 0);
    acc[2 * Q][fc] = __builtin_amdgcn_mfma_f32_16x16x32_bf16(
        af[0][1], bfr[fc][1], acc[2 * Q][fc], 0, 0, 0);
    acc[2 * Q + 1][fc] = __builtin_amdgcn_mfma_f32_16x16x32_bf16(
        af[1][1], bfr[fc][1], acc[2 * Q + 1][fc], 0, 0, 0);
  }
}

// asm s_barrier with memory clobber: a COMPILER memory fence (ds_read and
// global_load_lds cannot cross), while register-only MFMA/VALU stay free.
#define BAR asm volatile("s_barrier" ::: "memory")

// barrier -> wait own ds_reads -> pin (rule #18: MFMA would hoist past lgkm)
#define PH_HEAD                                         \
  do {                                                  \
    BAR;                                                \
    asm volatile("s_waitcnt lgkmcnt(0)" ::: "memory");  \
    __builtin_amdgcn_sched_barrier(0);                  \
  } while (0)

#define PH_TAIL(Q)                                      \
  do {                                                  \
    __builtin_amdgcn_s_setprio(1);                      \
    mfma_quad<Q>(acc, af, bfr);                         \
    __builtin_amdgcn_s_setprio(0);                      \
    BAR;                                                \
  } while (0)

#define STG_A(tile, half)                                                 \
  if ((tile) < NT)                                                        \
  stage_half(gA + (long)(half) * 128 * lda + (long)(tile) * 64,           \
             As + (((tile)&1) * 2 + (half)) * 8192 + wofs, lda64)

#define STG_B(tile, half)                                                 \
  if ((tile) < NT)                                                        \
  stage_half(gB + (long)(half) * 128 * ldb + (long)(tile) * 64,           \
             Bs + (((tile)&1) * 2 + (half)) * 8192 + wofs, ldb64)

// ---------------------------------------------------------------------------
// 256x256-tile bf16 GEMM, BK=64, 8 waves (2M x 4N), 8-phase schedule with
// counted vmcnt, st-swizzled LDS.  Used for scores and PV (large grids / long
// K).  C = A (MxK, lda) * Bt^T (Bt: NxK, ldb).
// EPI: 0 = f32 out, 1 = bf16 out.
// ---------------------------------------------------------------------------
template <int EPI, bool BIAS>
__global__ __launch_bounds__(512, 2) void gemm256(
    const u16* __restrict__ A, long lda, long sA, const u16* __restrict__ Bt,
    long ldb, long sB, void* __restrict__ Cout, long ldc, long sC,
    const float* __restrict__ bias, int NT, u16* __restrict__ VTout) {
  __shared__ u16 As[32768];  // [buf2][half2][128][64]
  __shared__ u16 Bs[32768];

  const int z = blockIdx.z;
  A += (long)z * sA;
  Bt += (long)z * sB;

  const int tid = threadIdx.x;
  const int w = tid >> 6, lane = tid & 63;
  const int wm = w >> 2, wn = w & 3;
  const int g = lane >> 4, l15 = lane & 15, l7 = lane & 7;
  const int m0 = blockIdx.x * 256;
  const int n0 = blockIdx.y * 256;

  // ds_read swizzled lane offsets (elements): slot = (ks*4+g) ^ (row&7)
  const u32 off0 = (u32)(((0 + g) ^ l7) * 8);
  const u32 off1 = (u32)(((4 + g) ^ l7) * 8);
  const u16* pA = As + wm * 8192 + l15 * 64;
  const u16* pB = Bs + (wn >> 1) * 8192 + ((wn & 1) * 64 + l15) * 64;

  // staging: thread t covers LDS bytes t*16 of an 8KB chunk; source column
  // pre-swizzled so LDS content obeys slot ^= row&7.
  const int trow = tid >> 3;
  const int perm = (tid & 7) ^ ((tid >> 3) & 7);
  const u16* gA = A + (long)(m0 + trow) * lda + perm * 8;
  const u16* gB = Bt + (long)(n0 + trow) * ldb + perm * 8;
  const long lda64 = lda * 64, ldb64 = ldb * 64;
  const u32 wofs = w * 512;  // elements; + lane*16B implicit in DMA

  f32x4 acc[8][4];
#pragma unroll
  for (int i = 0; i < 8; ++i)
#pragma unroll
    for (int j = 0; j < 4; ++j) acc[i][j] = (f32x4){0.f, 0.f, 0.f, 0.f};

  // prologue: tile0 (A+B) -> buf0, tile1 B -> buf1; wait leaves B(1) in flight
  stage_half(gA, As + 0 * 8192 + wofs, lda64);
  stage_half(gA + 128 * lda, As + 1 * 8192 + wofs, lda64);
  stage_half(gB, Bs + 0 * 8192 + wofs, ldb64);
  stage_half(gB + 128 * ldb, Bs + 1 * 8192 + wofs, ldb64);
  stage_half(gB + 64, Bs + 2 * 8192 + wofs, ldb64);
  stage_half(gB + 128 * ldb + 64, Bs + 3 * 8192 + wofs, ldb64);
  asm volatile("s_waitcnt vmcnt(4)" ::: "memory");
  BAR;

  bf16x8 af[2][2], bfr[4][2];
  const int niter = NT >> 1;
  for (int it = 0; it < niter; ++it) {
    const int t0 = it * 2;
    // ---- tile t0 (buf0) ----
    dsb(bfr, pB, off0, off1);  // ph1
    dsa(af, pA, off0, off1);
    STG_A(t0 + 1, 0);
    STG_A(t0 + 1, 1);
    PH_HEAD;
    PH_TAIL(0);
    dsa(af, pA + 2048, off0, off1);  // ph2
    STG_B(t0 + 2, 0);
    PH_HEAD;
    PH_TAIL(1);
    dsa(af, pA + 4096, off0, off1);  // ph3
    STG_B(t0 + 2, 1);
    PH_HEAD;
    PH_TAIL(2);
    dsa(af, pA + 6144, off0, off1);  // ph4
    if (it + 1 == niter) {
      asm volatile("s_waitcnt vmcnt(0)" ::: "memory");
    } else {
      asm volatile("s_waitcnt vmcnt(4)" ::: "memory");
    }
    PH_HEAD;
    PH_TAIL(3);
    // ---- tile t0+1 (buf1) ----
    dsb(bfr, pB + 16384, off0, off1);  // ph5
    dsa(af, pA + 16384, off0, off1);
    STG_A(t0 + 2, 0);
    STG_A(t0 + 2, 1);
    PH_HEAD;
    PH_TAIL(0);
    dsa(af, pA + 16384 + 2048, off0, off1);  // ph6
    STG_B(t0 + 3, 0);
    PH_HEAD;
    PH_TAIL(1);
    dsa(af, pA + 16384 + 4096, off0, off1);  // ph7
    STG_B(t0 + 3, 1);
    PH_HEAD;
    PH_TAIL(2);
    dsa(af, pA + 16384 + 6144, off0, off1);  // ph8
    asm volatile("s_waitcnt vmcnt(4)" ::: "memory");
    PH_HEAD;
    PH_TAIL(3);
  }

  // epilogue: C/D layout col = lane&15, row = (lane>>4)*4 + reg
  const int erow0 = m0 + wm * 128 + (lane >> 4) * 4;
  const int ecol0 = n0 + wn * 64 + l15;
#pragma unroll
  for (int fr = 0; fr < 8; ++fr) {
#pragma unroll
    for (int fc = 0; fc < 4; ++fc) {
      const int col = ecol0 + fc * 16;
      const float badd = BIAS ? bias[col] : 0.f;
#pragma unroll
      for (int r = 0; r < 4; ++r) {
        const long row = erow0 + fr * 16 + r;
        const float v = acc[fr][fc][r] + badd;
        if (EPI == 0) {
          ((float*)Cout)[(long)z * sC + row * ldc + col] = v;
        } else if (EPI == 1) {
          ((u16*)Cout)[(long)z * sC + row * ldc + col] = f2bf(v);
        } else {
          if (n0 < 1536) {
            ((u16*)Cout)[row * ldc + col] = f2bf(v);
          } else {
            const long b = row >> 12, s = row & 4095;
            VTout[(b * 768 + (col - 1536)) * 4096 + s] = f2bf(v);
          }
        }
      }
    }
  }
}

// ---------------------------------------------------------------------------
// 128x128-tile QKV projection GEMM (round-1-validated m97 structure: BK=32,
// 4 waves, 16 KiB LDS -> many blocks/CU resident; best for short-K skinny
// shapes).  A: 16384x768 bf16, Bt: Wcat 2304x768 bf16.
// cols<1536 -> QK[row*1536+col] (+bias); cols>=1536 -> VT[b][d][s] (+bias).
// ---------------------------------------------------------------------------
__global__ __launch_bounds__(256) void gemm128_qkv(
    const u16* __restrict__ A, const u16* __restrict__ Bt,
    u16* __restrict__ QK, const float* __restrict__ bias,
    u16* __restrict__ VT) {
  const int K = 768;
  __shared__ u16 As[128 * 32];
  __shared__ u16 Bs[128 * 32];

  const int tid = threadIdx.x;
  const int lane = tid & 63;
  const int w = tid >> 6;
  const int wr = w >> 1;
  const int wc = w & 1;
  const int m0 = blockIdx.x * 128;
  const int n0 = blockIdx.y * 128;

  const int srow = tid >> 2;
  const int scol = (tid & 3) * 8;
  const u16* gA0 = A + (long)(m0 + srow) * K + scol;
  const u16* gA1 = gA0 + (long)64 * K;
  const u16* gB0 = Bt + (long)(n0 + srow) * K + scol;
  const u16* gB1 = gB0 + (long)64 * K;
  u16* lA = As + w * 512;
  u16* lB = Bs + w * 512;

  f32x4 acc[4][4];
#pragma unroll
  for (int i = 0; i < 4; ++i)
#pragma unroll
    for (int j = 0; j < 4; ++j) acc[i][j] = (f32x4){0.f, 0.f, 0.f, 0.f};

  const u16* rA = As + (wr * 64 + (lane & 15)) * 32 + (lane >> 4) * 8;
  const u16* rB = Bs + (wc * 64 + (lane & 15)) * 32 + (lane >> 4) * 8;

  for (int kt = 0; kt < 24; ++kt) {
    const int ko = kt * 32;
    __syncthreads();
    gload16(gA0 + ko, lA);
    gload16(gA1 + ko, lA + 2048);
    gload16(gB0 + ko, lB);
    gload16(gB1 + ko, lB + 2048);
    __syncthreads();
    bf16x8 af[4], bfr[4];
#pragma unroll
    for (int m = 0; m < 4; ++m) af[m] = *(const bf16x8*)(rA + m * 512);
#pragma unroll
    for (int n = 0; n < 4; ++n) bfr[n] = *(const bf16x8*)(rB + n * 512);
#pragma unroll
    for (int m = 0; m < 4; ++m)
#pragma unroll
      for (int n = 0; n < 4; ++n)
        acc[m][n] = __builtin_amdgcn_mfma_f32_16x16x32_bf16(af[m], bfr[n],
                                                            acc[m][n], 0, 0, 0);
  }

  const int crow0 = m0 + wr * 64 + (lane >> 4) * 4;
  const int ccol0 = n0 + wc * 64 + (lane & 15);
#pragma unroll
  for (int m = 0; m < 4; ++m) {
#pragma unroll
    for (int n = 0; n < 4; ++n) {
      const int col = ccol0 + n * 16;
      const float badd = bias[col];
#pragma unroll
      for (int r = 0; r < 4; ++r) {
        const long row = crow0 + m * 16 + r;
        const float v = acc[m][n][r] + badd;
        if (col < 1536) {
          QK[row * 1536 + col] = f2bf(v);
        } else {
          const long b = row >> 12, s = row & 4095;
          VT[(b * 768 + (col - 1536)) * 4096 + s] = f2bf(v);
        }
      }
    }
  }
}

// ---------------------------------------------------------------------------
__global__ __launch_bounds__(256) void f32_to_bf16_kernel(
    const float* __restrict__ in, u16* __restrict__ out, long n) {
  long i0 = (long)blockIdx.x * 256 + threadIdx.x;
  long stride = (long)gridDim.x * 256;
  long n4 = n >> 2;
  for (long i = i0; i < n4; i += stride) {
    float4 f = ((const float4*)in)[i];
    ushort4 o = make_ushort4(f2bf(f.x), f2bf(f.y), f2bf(f.z), f2bf(f.w));
    ((ushort4*)out)[i] = o;
  }
}

// Wcat_t[2304][768] = concat(Wq^T * qs, Wk^T, Wv^T) as bf16
__global__ __launch_bounds__(256) void wcat_kernel(
    const float* __restrict__ Wq, const float* __restrict__ Wk,
    const float* __restrict__ Wv, u16* __restrict__ Wt, float qs) {
  __shared__ float t[64][65];
  const int kt = blockIdx.x;  // 0..11
  const int nt = blockIdx.y;  // 0..35
  const int sel = nt / 12;
  const float* W = sel == 0 ? Wq : (sel == 1 ? Wk : Wv);
  const float scale = sel == 0 ? qs : 1.f;
  const int n0 = (nt % 12) * 64, k0 = kt * 64;
#pragma unroll
  for (int i = 0; i < 16; ++i) {
    int idx = i * 256 + threadIdx.x;
    int r = idx >> 6, c = idx & 63;
    t[r][c] = W[(long)(k0 + r) * 768 + (n0 + c)];
  }
  __syncthreads();
#pragma unroll
  for (int i = 0; i < 16; ++i) {
    int idx = i * 256 + threadIdx.x;
    int ro = idx >> 6, co = idx & 63;
    Wt[(long)(nt * 64 + ro) * 768 + (k0 + co)] = f2bf(t[co][ro] * scale);
  }
}

__global__ __launch_bounds__(256) void bcat_kernel(
    const float* __restrict__ bq, const float* __restrict__ bk,
    const float* __restrict__ bv, float* __restrict__ bc, float qs) {
  int i = blockIdx.x * 256 + threadIdx.x;
  if (i < 2304)
    bc[i] = i < 768 ? bq[i] * qs : (i < 1536 ? bk[i - 768] : bv[i - 1536]);
}

// in-place row softmax over 4096 bf16 per row; one block (256 thr) per row.
__global__ __launch_bounds__(256) void softmax_rows_kernel(u16* __restrict__ Sd) {
  const long row = blockIdx.x;
  u16* p = Sd + row * 4096;
  const int tid = threadIdx.x;
  u16x8 a0 = *(const u16x8*)(p + tid * 8);
  u16x8 a1 = *(const u16x8*)(p + 2048 + tid * 8);
  float v[16];
#pragma unroll
  for (int j = 0; j < 8; ++j) {
    v[j] = bf2f(a0[j]);
    v[8 + j] = bf2f(a1[j]);
  }
  float mx = v[0];
#pragma unroll
  for (int j = 1; j < 16; ++j) mx = fmaxf(mx, v[j]);
#pragma unroll
  for (int o = 32; o > 0; o >>= 1) mx = fmaxf(mx, __shfl_xor(mx, o, 64));
  __shared__ float red[8];
  if ((tid & 63) == 0) red[tid >> 6] = mx;
  __syncthreads();
  mx = fmaxf(fmaxf(red[0], red[1]), fmaxf(red[2], red[3]));
  float e[16], s = 0.f;
  const float L2E = 1.4426950408889634f;
#pragma unroll
  for (int j = 0; j < 16; ++j) {
    e[j] = exp2f((v[j] - mx) * L2E);
    s += e[j];
  }
#pragma unroll
  for (int o = 32; o > 0; o >>= 1) s += __shfl_xor(s, o, 64);
  if ((tid & 63) == 0) red[4 + (tid >> 6)] = s;
  __syncthreads();
  s = (red[4] + red[5]) + (red[6] + red[7]);
  const float inv = 1.f / s;
  u16x8 o0, o1;
#pragma unroll
  for (int j = 0; j < 8; ++j) {
    o0[j] = f2bf(e[j] * inv);
    o1[j] = f2bf(e[8 + j] * inv);
  }
  *(u16x8*)(p + tid * 8) = o0;
  *(u16x8*)(p + 2048 + tid * 8) = o1;
}

// ---------------------------------------------------------------------------
extern "C" void kernel_launch(void* const* d_in, const int* in_sizes, int n_in,
                              void* d_out, int out_size, void* d_ws,
                              size_t ws_size, hipStream_t stream) {
  const float* x = (const float*)d_in[0];
  const float* Wq = (const float*)d_in[1];
  const float* bq = (const float*)d_in[2];
  const float* Wk = (const float*)d_in[3];
  const float* bk = (const float*)d_in[4];
  const float* Wv = (const float*)d_in[5];
  const float* bv = (const float*)d_in[6];
  float* out = (float*)d_out;

  const float qs = 0.036084391824351615f;  // 1/sqrt(768)

  // workspace carve
  char* p = (char*)d_ws;
  u16* Wcat = (u16*)p;  p += (size_t)2304 * 768 * 2;   // 3.54 MB
  float* bc = (float*)p; p += (size_t)2304 * 4;         // 9.2 KB
  u16* xbf = (u16*)p;   p += (size_t)16384 * 768 * 2;  // 25.2 MB
  u16* QK = (u16*)p;    p += (size_t)16384 * 1536 * 2; // 50.3 MB
  u16* VT = (u16*)p;    p += (size_t)4 * 768 * 4096 * 2; // 25.2 MB
  u16* Sbuf = (u16*)p;
  const size_t base = (size_t)(p - (char*)d_ws);
  const size_t sOne = (size_t)4096 * 4096 * 2;  // 33.6 MB
  int grp = 1;
  if (ws_size >= base + 4 * sOne) grp = 4;
  else if (ws_size >= base + 2 * sOne) grp = 2;

  f32_to_bf16_kernel<<<2048, 256, 0, stream>>>(x, xbf, (long)16384 * 768);
  wcat_kernel<<<dim3(12, 36), 256, 0, stream>>>(Wq, Wk, Wv, Wcat, qs);
  bcat_kernel<<<9, 256, 0, stream>>>(bq, bk, bv, bc, qs);

  // fused QKV projection on the 128^2 high-occupancy structure:
  // A=xbf (16384x768), Bt=Wcat (2304x768); cols<1536 -> QK, else -> VT.
  gemm128_qkv<<<dim3(128, 18), 256, 0, stream>>>(xbf, Wcat, QK, bc, VT);

  for (int b0 = 0; b0 < 4; b0 += grp) {
    // scores: A=Q (cols 0-767 of QK), Bt=K (cols 768-1535), per batch
    gemm256<1, false><<<dim3(16, 16, grp), 512, 0, stream>>>(
        QK + (long)b0 * 4096 * 1536, 1536, (long)4096 * 1536,
        QK + 768 + (long)b0 * 4096 * 1536, 1536, (long)4096 * 1536, Sbuf, 4096,
        (long)4096 * 4096, nullptr, 12, nullptr);
    softmax_rows_kernel<<<grp * 4096, 256, 0, stream>>>(Sbuf);
    // out = P * V: A=Sbuf, Bt=VT (768x4096 per batch)
    gemm256<0, false><<<dim3(16, 3, grp), 512, 0, stream>>>(
        Sbuf, 4096, (long)4096 * 4096, VT + (long)b0 * 768 * 4096, 4096,
        (long)768 * 4096, out + (long)b0 * 4096 * 768, 768, (long)4096 * 768,
        nullptr, 64, nullptr);
  }
}